// Round 6
// baseline (1208.313 us; speedup 1.0000x reference)
//
#include <hip/hip_runtime.h>
#include <stdint.h>

#define BB 8
#define NN 8192
#define NPOINT 1024
#define NSAMPLE 32
#define XS 104   // x row stride in bf16 elems (cols: 0..63 feat, 64..66 xyz, 67..95 zero)
#define HS 72    // h / w2 / w3 row stride in bf16 elems (cols 0..63 used)

typedef short short8 __attribute__((ext_vector_type(8)));
typedef float floatx4 __attribute__((ext_vector_type(4)));
typedef float f32x2 __attribute__((ext_vector_type(2)));

__device__ __forceinline__ unsigned short f2bf(float f) {
    unsigned u = __float_as_uint(f);
    unsigned r = u + 0x7FFFu + ((u >> 16) & 1u);   // RNE to bf16
    return (unsigned short)(r >> 16);
}

__device__ __forceinline__ unsigned long long u64max(unsigned long long a,
                                                     unsigned long long b) {
    return (a > b) ? a : b;
}

template <int CTRL, int RMASK>
__device__ __forceinline__ unsigned long long dpp_max_step(unsigned long long key) {
    int lo = (int)(unsigned int)(key & 0xffffffffull);
    int hi = (int)(unsigned int)(key >> 32);
    int tlo = __builtin_amdgcn_update_dpp(0, lo, CTRL, RMASK, 0xF, true);
    int thi = __builtin_amdgcn_update_dpp(0, hi, CTRL, RMASK, 0xF, true);
    unsigned long long t = ((unsigned long long)(unsigned int)thi << 32) |
                           (unsigned long long)(unsigned int)tlo;
    return u64max(key, t);
}

__device__ __forceinline__ unsigned long long dpp_wave_max(unsigned long long key) {
    key = dpp_max_step<0x111, 0xF>(key);  // row_shr:1
    key = dpp_max_step<0x112, 0xF>(key);  // row_shr:2
    key = dpp_max_step<0x114, 0xF>(key);  // row_shr:4
    key = dpp_max_step<0x118, 0xF>(key);  // row_shr:8
    key = dpp_max_step<0x142, 0xA>(key);  // row_bcast:15
    key = dpp_max_step<0x143, 0xC>(key);  // row_bcast:31
    return key;
}

// Barrier that does NOT drain vmcnt: LDS ordering only. The FPS loop's global
// stores (new_xyz rows + sel publishes) have no intra-block consumer, so the
// compiler-lowered __syncthreads vmcnt(0) drain is pure stall. (Measured
// neutral vs __syncthreads in R11; kept because it cannot be slower.)
__device__ __forceinline__ void fps_bar() {
    asm volatile("s_waitcnt lgkmcnt(0)" ::: "memory");
    __builtin_amdgcn_s_barrier();
    asm volatile("" ::: "memory");
}

// ---------------------------------------------------------------------------
// MEGA KERNEL (256-thread blocks). Blocks 0..7: FPS (one per batch, 4 waves,
// 32 pts/thread). Blocks 8..2055: consumers (b=i&7, g=i>>3), 4 centroids each:
// spin on sel[] (relaxed agent atomics; payload=idx+1), then ball query +
// bf16-MFMA MLP + maxpool, hidden behind the fps-paced wait.
//
// R12: remove the second dependent LDS round trip from the FPS iteration.
// Winner COORDS are carried through the reduction: each thread tracks its
// best candidate's (x,y,z) in-loop (issue-cost shown ~free by R8's packed
// null result); after the u64-key DPP wave max, the unique winning lane
// (keys embed ~p, globally unique) writes {key, x, y, z} to LDS; post-barrier
// all threads read 4 keys + 4 coord triples in ONE batch of independent LDS
// reads and select key+coords with a cmp/cndmask tree. The old dependent
// sx[cur]/sy/sz read — and the 96KB sx/sy/sz staging entirely — are gone.
// Coords pass through cndmask/LDS only => bit-identical to xyz[cur].
// ---------------------------------------------------------------------------
__global__ __launch_bounds__(256) void mega_kernel(
    const float* __restrict__ xyz, const float* __restrict__ features,
    const float* __restrict__ w1, const float* __restrict__ b1,
    const float* __restrict__ w2, const float* __restrict__ b2,
    const float* __restrict__ w3, const float* __restrict__ b3,
    float* __restrict__ new_xyz, float* __restrict__ out_feat,
    unsigned* __restrict__ sel) {
    __shared__ __align__(16) char smem[98432];

    const int t = threadIdx.x;
    const int lane = t & 63;

    if (blockIdx.x < BB) {
        // =================== FPS (4 waves, coords-through-reduce) ===========
#pragma clang fp contract(off)
        const int b = blockIdx.x;
        unsigned long long* keysA = (unsigned long long*)smem;  // [2][4] u64
        float* coordA = (float*)(smem + 64);                    // [2][4][3] f32
        const int wv = t >> 6;
        const float* base = xyz + (size_t)b * NN * 3;
        unsigned* selb = sel + b * NPOINT;

        f32x2 px2[16], py2[16], pz2[16];
        float dist[32];
#pragma unroll
        for (int i = 0; i < 32; ++i) {
            int p = t + (i << 8);               // coalesced global load
            float x = base[p * 3 + 0];
            float y = base[p * 3 + 1];
            float z = base[p * 3 + 2];
            if (i & 1) { px2[i >> 1].y = x; py2[i >> 1].y = y; pz2[i >> 1].y = z; }
            else       { px2[i >> 1].x = x; py2[i >> 1].x = y; pz2[i >> 1].x = z; }
            dist[i] = 1e10f;                    // f32(10000000000.0) exact
        }

        float lx = base[0], ly = base[1], lz = base[2];   // point 0 (uniform)
        float* outb = new_xyz + (size_t)b * NPOINT * 3;
        if (t == 0) {
            outb[0] = lx; outb[1] = ly; outb[2] = lz;
            __hip_atomic_store(&selb[0], 1u, __ATOMIC_RELAXED,
                               __HIP_MEMORY_SCOPE_AGENT);
        }

        for (int j = 1; j < NPOINT; ++j) {
            float bd0 = -1.0f, bd1 = -1.0f;
            int bi0 = 0, bi1 = 16;
            float bx0 = 0.f, by0 = 0.f, bz0 = 0.f;
            float bx1 = 0.f, by1 = 0.f, bz1 = 0.f;
            f32x2 lx2; lx2.x = lx; lx2.y = lx;
            f32x2 ly2; ly2.x = ly; ly2.y = ly;
            f32x2 lz2; lz2.x = lz; lz2.y = lz;
#pragma unroll
            for (int jj = 0; jj < 16; ++jj) {
                // packed (v_pk_add_f32 / v_pk_mul_f32, IEEE RN, no contraction)
                f32x2 dx = px2[jj] - lx2;
                f32x2 dy = py2[jj] - ly2;
                f32x2 dz = pz2[jj] - lz2;
                f32x2 xx = dx * dx;
                f32x2 yy = dy * dy;
                f32x2 zz = dz * dz;
                f32x2 s1 = xx + yy;
                f32x2 d2 = s1 + zz;
                float d0 = fminf(dist[2 * jj], d2.x);
                dist[2 * jj] = d0;
                float d1 = fminf(dist[2 * jj + 1], d2.y);
                dist[2 * jj + 1] = d1;
                // within-pair argmax: >= prefers even slot (lower point idx)
                bool ge = d0 >= d1;
                float pm = ge ? d0 : d1;
                int pi = ge ? (2 * jj) : (2 * jj + 1);
                float pxc = ge ? px2[jj].x : px2[jj].y;
                float pyc = ge ? py2[jj].x : py2[jj].y;
                float pzc = ge ? pz2[jj].x : pz2[jj].y;
                if (jj < 8) {            // chain A: elems 0..15 (lower indices)
                    bool gt = pm > bd0;
                    bd0 = gt ? pm : bd0;
                    bi0 = gt ? pi : bi0;
                    bx0 = gt ? pxc : bx0;
                    by0 = gt ? pyc : by0;
                    bz0 = gt ? pzc : bz0;
                } else {                 // chain B: elems 16..31
                    bool gt = pm > bd1;
                    bd1 = gt ? pm : bd1;
                    bi1 = gt ? pi : bi1;
                    bx1 = gt ? pxc : bx1;
                    by1 = gt ? pyc : by1;
                    bz1 = gt ? pzc : bz1;
                }
            }
            // thread-local best: tie -> chain A (lower indices)
            bool geAB = bd0 >= bd1;
            float bd = geAB ? bd0 : bd1;
            int bi = geAB ? bi0 : bi1;
            float bx = geAB ? bx0 : bx1;
            float by = geAB ? by0 : by1;
            float bz = geAB ? bz0 : bz1;

            unsigned long long key =
                ((unsigned long long)__float_as_uint(bd) << 32) |
                (unsigned long long)(~(unsigned int)(t + (bi << 8)));
            unsigned long long kk = dpp_wave_max(key);
            unsigned wlo = (unsigned)__builtin_amdgcn_readlane(
                (int)(unsigned)(kk & 0xffffffffull), 63);
            unsigned whi = (unsigned)__builtin_amdgcn_readlane(
                (int)(unsigned)(kk >> 32), 63);
            // unique winning lane (keys globally unique via ~p) publishes
            if ((unsigned)(key >> 32) == whi &&
                (unsigned)(key & 0xffffffffull) == wlo) {
                int e = ((j & 1) << 2) + wv;
                keysA[e] = key;
                float* c = &coordA[e * 3];
                c[0] = bx; c[1] = by; c[2] = bz;
            }
            fps_bar();

            // one batch of independent LDS reads: 4 keys + 4 coord triples
            int cur;
            {
                const unsigned long long* kr = &keysA[(j & 1) << 2];
                ulonglong2 k01 = *(const ulonglong2*)&kr[0];
                ulonglong2 k23 = *(const ulonglong2*)&kr[2];
                const float4* cr4 = (const float4*)&coordA[(j & 1) * 12];
                float4 q0 = cr4[0], q1 = cr4[1], q2 = cr4[2];
                // entry coords: e0=(q0.x,q0.y,q0.z) e1=(q0.w,q1.x,q1.y)
                //               e2=(q1.z,q1.w,q2.x) e3=(q2.y,q2.z,q2.w)
                bool s01 = k01.x > k01.y;               // keys unique: > == >=
                unsigned long long ka = s01 ? k01.x : k01.y;
                float ax = s01 ? q0.x : q0.w;
                float ay = s01 ? q0.y : q1.x;
                float az = s01 ? q0.z : q1.y;
                bool s23 = k23.x > k23.y;
                unsigned long long kb = s23 ? k23.x : k23.y;
                float bxx = s23 ? q1.z : q2.y;
                float byy = s23 ? q1.w : q2.z;
                float bzz = s23 ? q2.x : q2.w;
                bool sab = ka > kb;
                unsigned long long kf = sab ? ka : kb;
                lx = sab ? ax : bxx;
                ly = sab ? ay : byy;
                lz = sab ? az : bzz;
                cur = (int)(~(unsigned int)(kf & 0xffffffffull));
            }
            if (t == 0) {
                outb[j * 3 + 0] = lx;
                outb[j * 3 + 1] = ly;
                outb[j * 3 + 2] = lz;
                __hip_atomic_store(&selb[j], (unsigned)(cur + 1),
                                   __ATOMIC_RELAXED, __HIP_MEMORY_SCOPE_AGENT);
            }
        }
    } else {
        // =================== consumer: ballq + MFMA MLP =====================
        const int i = blockIdx.x - BB;
        const int b = i & 7;                   // batch
        const int g = i >> 3;                  // centroid group (4 centroids)
        unsigned short* s_x = (unsigned short*)smem;            // 128*XS
        unsigned short* s_h = (unsigned short*)(smem + 26624);  // 128*HS
        unsigned short* s_w12 = (unsigned short*)(smem + 45056);// 11264 elems
        int* s_gi = (int*)(smem + 67584);                       // 128
        int* s_sel4 = (int*)(smem + 68096);                     // 4

        const int w = t >> 6;
        const int col = lane & 15;
        const int quad = lane >> 4;

        // ---- stage w1, w2 (independent of fps progress) ----
        {
            int o = t >> 2, part = t & 3;
            const float* w1r = w1 + o * 67;
#pragma unroll
            for (int ii = 0; ii < 26; ++ii) {
                int c = part * 26 + ii;
                float v = 0.0f;
                if (c < 64) v = w1r[3 + c];           // permuted: feats first
                else if (c < 67) v = w1r[c - 64];     // then xyz cols
                s_w12[o * XS + c] = f2bf(v);
            }
            const float* w2r = w2 + o * 64 + part * 16;
#pragma unroll
            for (int ii = 0; ii < 8; ++ii) {
                unsigned pk = (unsigned)f2bf(w2r[2 * ii]) |
                              ((unsigned)f2bf(w2r[2 * ii + 1]) << 16);
                *(unsigned*)&s_w12[6656 + o * HS + part * 16 + 2 * ii] = pk;
            }
        }

        // ---- spin for the 4 centroid indices ----
        if (t < 4) {
            unsigned* sp = sel + b * NPOINT + (g << 2) + t;
            unsigned v;
            while ((( v = __hip_atomic_load(sp, __ATOMIC_RELAXED,
                                            __HIP_MEMORY_SCOPE_AGENT)) - 1u) > 8191u)
                __builtin_amdgcn_s_sleep(2);
            s_sel4[t] = (int)(v - 1u);
        }
        __syncthreads();

        // ---- ball query: wave w -> centroid s_sel4[w] ----
        {
            const int cidx = s_sel4[w];
            const float* base = xyz + (size_t)b * NN * 3;
            const float cx = base[cidx * 3 + 0];   // bit-identical to new_xyz
            const float cy = base[cidx * 3 + 1];
            const float cz = base[cidx * 3 + 2];
            const float R2 = (float)(0.4 * 0.4);   // 0.15999999642f

            int have = 0;
            for (int chunk = 0; chunk < (NN / 64) && have < NSAMPLE; ++chunk) {
                int p = (chunk << 6) + lane;
                float dx = __fsub_rn(cx, base[p * 3 + 0]);
                float dy = __fsub_rn(cy, base[p * 3 + 1]);
                float dz = __fsub_rn(cz, base[p * 3 + 2]);
                float d2 = __fadd_rn(__fadd_rn(__fmul_rn(dx, dx), __fmul_rn(dy, dy)),
                                     __fmul_rn(dz, dz));
                bool in = d2 < R2;
                unsigned long long m = __ballot(in);
                int pre = __popcll(m & ((1ull << lane) - 1ull));
                int slot = have + pre;
                if (in && slot < NSAMPLE) s_gi[w * NSAMPLE + slot] = p;
                have += (int)__popcll(m);
            }
            if (lane < NSAMPLE) {
                int first = s_gi[w * NSAMPLE];    // centroid always hits
                int v = (lane < have) ? s_gi[w * NSAMPLE + lane] : first;
                s_gi[w * NSAMPLE + lane] = v;
            }
        }
        __syncthreads();

        // ---- gather x = [feat(64) | xyz_rel(3) | zeros] in bf16 ----
        {
            int k = t >> 1, half = t & 1;
            int row = s_gi[k];
            const float4* frow =
                (const float4*)(features + ((size_t)b * NN + row) * 64) + half * 8;
            unsigned short* xr = &s_x[k * XS + half * 32];
#pragma unroll
            for (int ii = 0; ii < 8; ++ii) {
                float4 v = frow[ii];
                unsigned lo = (unsigned)f2bf(v.x) | ((unsigned)f2bf(v.y) << 16);
                unsigned hi = (unsigned)f2bf(v.z) | ((unsigned)f2bf(v.w) << 16);
                *(uint2*)(xr + ii * 4) = make_uint2(lo, hi);
            }
        }
        if (t < 128) {
            int k = t;
            int row = s_gi[k];
            int cidx = s_sel4[k >> 5];
            const float* pr = xyz + ((size_t)b * NN + row) * 3;
            const float* cr = xyz + ((size_t)b * NN + cidx) * 3;
            s_x[k * XS + 64] = f2bf(pr[0] - cr[0]);
            s_x[k * XS + 65] = f2bf(pr[1] - cr[1]);
            s_x[k * XS + 66] = f2bf(pr[2] - cr[2]);
            s_x[k * XS + 67] = 0;
            unsigned* z = (unsigned*)&s_x[k * XS + 68];
#pragma unroll
            for (int ii = 0; ii < 14; ++ii) z[ii] = 0;    // cols 68..95
        }
        __syncthreads();

        const int mbase = w * 32;

        // ---- Layer 1: [128 x 96] x [96 -> 64] ----
        floatx4 acc[2][4] = {};
        for (int kk = 0; kk < 3; ++kk) {
            short8 a0 = *(const short8*)&s_x[(mbase + col) * XS + kk * 32 + quad * 8];
            short8 a1 = *(const short8*)&s_x[(mbase + 16 + col) * XS + kk * 32 + quad * 8];
#pragma unroll
            for (int nt = 0; nt < 4; ++nt) {
                short8 bfr = *(const short8*)&s_w12[(nt * 16 + col) * XS + kk * 32 + quad * 8];
                acc[0][nt] = __builtin_amdgcn_mfma_f32_16x16x32_bf16(a0, bfr, acc[0][nt], 0, 0, 0);
                acc[1][nt] = __builtin_amdgcn_mfma_f32_16x16x32_bf16(a1, bfr, acc[1][nt], 0, 0, 0);
            }
        }
#pragma unroll
        for (int nt = 0; nt < 4; ++nt) {
            float bb = b1[nt * 16 + col];
#pragma unroll
            for (int mt = 0; mt < 2; ++mt)
#pragma unroll
                for (int r = 0; r < 4; ++r) {
                    float v = fmaxf(acc[mt][nt][r] + bb, 0.0f);
                    s_h[(mbase + mt * 16 + quad * 4 + r) * HS + nt * 16 + col] = f2bf(v);
                }
        }
        __syncthreads();

        // ---- Layer 2: [128 x 64] x [64 -> 64], h2 -> s_x region ----
        floatx4 acc2[2][4] = {};
        for (int kk = 0; kk < 2; ++kk) {
            short8 a0 = *(const short8*)&s_h[(mbase + col) * HS + kk * 32 + quad * 8];
            short8 a1 = *(const short8*)&s_h[(mbase + 16 + col) * HS + kk * 32 + quad * 8];
#pragma unroll
            for (int nt = 0; nt < 4; ++nt) {
                short8 bfr = *(const short8*)&s_w12[6656 + (nt * 16 + col) * HS + kk * 32 + quad * 8];
                acc2[0][nt] = __builtin_amdgcn_mfma_f32_16x16x32_bf16(a0, bfr, acc2[0][nt], 0, 0, 0);
                acc2[1][nt] = __builtin_amdgcn_mfma_f32_16x16x32_bf16(a1, bfr, acc2[1][nt], 0, 0, 0);
            }
        }
        unsigned short* s_h2 = s_x;  // x dead after L1
#pragma unroll
        for (int nt = 0; nt < 4; ++nt) {
            float bb = b2[nt * 16 + col];
#pragma unroll
            for (int mt = 0; mt < 2; ++mt)
#pragma unroll
                for (int r = 0; r < 4; ++r) {
                    float v = fmaxf(acc2[mt][nt][r] + bb, 0.0f);
                    s_h2[(mbase + mt * 16 + quad * 4 + r) * HS + nt * 16 + col] = f2bf(v);
                }
        }
        __syncthreads();   // h2 complete; all w2 reads done

        // ---- stage w3 [128][HS] over w1/w2 ----
        {
            int o = t >> 1, half = t & 1;
            const float* w3r = w3 + o * 64 + half * 32;
#pragma unroll
            for (int ii = 0; ii < 16; ++ii) {
                unsigned pk = (unsigned)f2bf(w3r[2 * ii]) |
                              ((unsigned)f2bf(w3r[2 * ii + 1]) << 16);
                *(unsigned*)&s_w12[o * HS + half * 32 + 2 * ii] = pk;
            }
        }
        __syncthreads();

        // ---- Layer 3: [128 x 64] x [64 -> 128], fused maxpool+bias+relu ----
        floatx4 c3[2][8] = {};
        for (int kk = 0; kk < 2; ++kk) {
            short8 a0 = *(const short8*)&s_h2[(mbase + col) * HS + kk * 32 + quad * 8];
            short8 a1 = *(const short8*)&s_h2[(mbase + 16 + col) * HS + kk * 32 + quad * 8];
#pragma unroll
            for (int nt = 0; nt < 8; ++nt) {
                short8 bfr = *(const short8*)&s_w12[(nt * 16 + col) * HS + kk * 32 + quad * 8];
                c3[0][nt] = __builtin_amdgcn_mfma_f32_16x16x32_bf16(a0, bfr, c3[0][nt], 0, 0, 0);
                c3[1][nt] = __builtin_amdgcn_mfma_f32_16x16x32_bf16(a1, bfr, c3[1][nt], 0, 0, 0);
            }
        }
        {
            int gg = (g << 2) + w;
            float* ob = out_feat + (size_t)b * (128 * 1024) + gg;
#pragma unroll
            for (int nt = 0; nt < 8; ++nt) {
                float m = fmaxf(fmaxf(fmaxf(c3[0][nt][0], c3[0][nt][1]),
                                      fmaxf(c3[0][nt][2], c3[0][nt][3])),
                                fmaxf(fmaxf(c3[1][nt][0], c3[1][nt][1]),
                                      fmaxf(c3[1][nt][2], c3[1][nt][3])));
                m = fmaxf(m, __shfl_xor(m, 16));
                m = fmaxf(m, __shfl_xor(m, 32));
                if (lane < 16) {
                    float v = fmaxf(m + b3[nt * 16 + lane], 0.0f);
                    ob[(size_t)(nt * 16 + lane) * 1024] = v;
                }
            }
        }
    }
}

extern "C" void kernel_launch(void* const* d_in, const int* in_sizes, int n_in,
                              void* d_out, int out_size, void* d_ws, size_t ws_size,
                              hipStream_t stream) {
    const float* xyz      = (const float*)d_in[0];
    const float* features = (const float*)d_in[1];
    const float* w1       = (const float*)d_in[2];
    const float* b1       = (const float*)d_in[3];
    const float* w2       = (const float*)d_in[4];
    const float* b2       = (const float*)d_in[5];
    const float* w3       = (const float*)d_in[6];
    const float* b3       = (const float*)d_in[7];

    float* out      = (float*)d_out;
    float* new_xyz  = out;                         // B*NPOINT*3
    float* out_feat = out + BB * NPOINT * 3;       // B*128*NPOINT
    unsigned* sel   = (unsigned*)d_ws;             // B*NPOINT u32; poison = not-ready

    mega_kernel<<<BB + (BB * NPOINT) / 4, 256, 0, stream>>>(
        xyz, features, w1, b1, w2, b2, w3, b3, new_xyz, out_feat, sel);
}

// Round 7
// 1008.028 us; speedup vs baseline: 1.1987x; 1.1987x over previous
//
#include <hip/hip_runtime.h>
#include <stdint.h>

#define BB 8
#define NN 8192
#define NPOINT 1024
#define NSAMPLE 32
#define XS 104   // x row stride in bf16 elems (cols: 0..63 feat, 64..66 xyz, 67..95 zero)
#define HS 72    // h / w2 / w3 row stride in bf16 elems (cols 0..63 used)

typedef short short8 __attribute__((ext_vector_type(8)));
typedef float floatx4 __attribute__((ext_vector_type(4)));
typedef float f32x2 __attribute__((ext_vector_type(2)));

__device__ __forceinline__ unsigned short f2bf(float f) {
    unsigned u = __float_as_uint(f);
    unsigned r = u + 0x7FFFu + ((u >> 16) & 1u);   // RNE to bf16
    return (unsigned short)(r >> 16);
}

__device__ __forceinline__ unsigned long long u64max(unsigned long long a,
                                                     unsigned long long b) {
    return (a > b) ? a : b;
}

template <int CTRL, int RMASK>
__device__ __forceinline__ unsigned long long dpp_max_step(unsigned long long key) {
    int lo = (int)(unsigned int)(key & 0xffffffffull);
    int hi = (int)(unsigned int)(key >> 32);
    int tlo = __builtin_amdgcn_update_dpp(0, lo, CTRL, RMASK, 0xF, true);
    int thi = __builtin_amdgcn_update_dpp(0, hi, CTRL, RMASK, 0xF, true);
    unsigned long long t = ((unsigned long long)(unsigned int)thi << 32) |
                           (unsigned long long)(unsigned int)tlo;
    return u64max(key, t);
}

__device__ __forceinline__ unsigned long long dpp_wave_max(unsigned long long key) {
    key = dpp_max_step<0x111, 0xF>(key);  // row_shr:1
    key = dpp_max_step<0x112, 0xF>(key);  // row_shr:2
    key = dpp_max_step<0x114, 0xF>(key);  // row_shr:4
    key = dpp_max_step<0x118, 0xF>(key);  // row_shr:8
    key = dpp_max_step<0x142, 0xA>(key);  // row_bcast:15
    key = dpp_max_step<0x143, 0xC>(key);  // row_bcast:31
    return key;
}

// Barrier that does NOT drain vmcnt: LDS ordering only. The FPS loop's global
// stores (new_xyz rows + sel publishes) have no intra-block consumer, so the
// compiler-lowered __syncthreads vmcnt(0) drain is pure stall. (Measured
// neutral vs __syncthreads in R11; kept because it cannot be slower.)
__device__ __forceinline__ void fps_bar() {
    asm volatile("s_waitcnt lgkmcnt(0)" ::: "memory");
    __builtin_amdgcn_s_barrier();
    asm volatile("" ::: "memory");
}

// ---------------------------------------------------------------------------
// MEGA KERNEL (256-thread blocks). Blocks 0..7: FPS (one per batch, 4 waves,
// 32 pts/thread). Blocks 8..2055: consumers (b=i&7, g=i>>3), 4 centroids each:
// spin on sel[] (relaxed agent atomics; payload=idx+1), then ball query +
// bf16-MFMA MLP + maxpool, hidden behind the fps-paced wait.
//
// R13: revert to the R11 champion structure (945us; R12's coords-through-
// reduce regressed +200us — in-loop coord cndmasks + VGPR 132->172). Two
// mechanism-safe trims on top:
//   (1) sx/sy/sz (3x 32KB planes) -> interleaved sxyz[p*3] (96KB): winner
//       fetch is ONE contiguous 12B broadcast read (wave-uniform addr)
//       instead of three 32KB-apart ds_read_b32; staging stays 2-way/bank.
//   (2) consumer spin s_sleep(2) -> s_sleep(32): cuts 8192 agent-scope
//       pollers' LLC/fabric traffic 16x; worst-case +0.9us on the final
//       consumer tail only.
// ---------------------------------------------------------------------------
__global__ __launch_bounds__(256) void mega_kernel(
    const float* __restrict__ xyz, const float* __restrict__ features,
    const float* __restrict__ w1, const float* __restrict__ b1,
    const float* __restrict__ w2, const float* __restrict__ b2,
    const float* __restrict__ w3, const float* __restrict__ b3,
    float* __restrict__ new_xyz, float* __restrict__ out_feat,
    unsigned* __restrict__ sel) {
    __shared__ __align__(16) char smem[98432];

    const int t = threadIdx.x;
    const int lane = t & 63;

    if (blockIdx.x < BB) {
        // =================== FPS (4 waves, u64-key DPP reduce) ==============
#pragma clang fp contract(off)
        const int b = blockIdx.x;
        float* sxyz = (float*)smem;                              // [8192][3]
        unsigned long long* wred = (unsigned long long*)(smem + 98304); // [2][4]
        const int wv = t >> 6;
        const float* base = xyz + (size_t)b * NN * 3;
        unsigned* selb = sel + b * NPOINT;

        f32x2 px2[16], py2[16], pz2[16];
        float dist[32];
#pragma unroll
        for (int i = 0; i < 32; ++i) {
            int p = t + (i << 8);               // coalesced glb; LDS 2-way/bank
            float x = base[p * 3 + 0];
            float y = base[p * 3 + 1];
            float z = base[p * 3 + 2];
            sxyz[p * 3 + 0] = x; sxyz[p * 3 + 1] = y; sxyz[p * 3 + 2] = z;
            if (i & 1) { px2[i >> 1].y = x; py2[i >> 1].y = y; pz2[i >> 1].y = z; }
            else       { px2[i >> 1].x = x; py2[i >> 1].x = y; pz2[i >> 1].x = z; }
            dist[i] = 1e10f;                    // f32(10000000000.0) exact
        }
        __syncthreads();

        float lx = sxyz[0], ly = sxyz[1], lz = sxyz[2];
        float* outb = new_xyz + (size_t)b * NPOINT * 3;
        if (t == 0) {
            outb[0] = lx; outb[1] = ly; outb[2] = lz;
            __hip_atomic_store(&selb[0], 1u, __ATOMIC_RELAXED,
                               __HIP_MEMORY_SCOPE_AGENT);
        }

        for (int j = 1; j < NPOINT; ++j) {
            float bd0 = -1.0f, bd1 = -1.0f;
            int bi0 = 0, bi1 = 16;
            f32x2 lx2; lx2.x = lx; lx2.y = lx;
            f32x2 ly2; ly2.x = ly; ly2.y = ly;
            f32x2 lz2; lz2.x = lz; lz2.y = lz;
#pragma unroll
            for (int jj = 0; jj < 16; ++jj) {
                // packed (v_pk_add_f32 / v_pk_mul_f32, IEEE RN, no contraction)
                f32x2 dx = px2[jj] - lx2;
                f32x2 dy = py2[jj] - ly2;
                f32x2 dz = pz2[jj] - lz2;
                f32x2 xx = dx * dx;
                f32x2 yy = dy * dy;
                f32x2 zz = dz * dz;
                f32x2 s1 = xx + yy;
                f32x2 d2 = s1 + zz;
                float d0 = fminf(dist[2 * jj], d2.x);
                dist[2 * jj] = d0;
                float d1 = fminf(dist[2 * jj + 1], d2.y);
                dist[2 * jj + 1] = d1;
                // within-pair argmax: >= prefers even slot (lower point idx)
                bool ge = d0 >= d1;
                float pm = ge ? d0 : d1;
                int pi = ge ? (2 * jj) : (2 * jj + 1);
                if (jj < 8) {            // chain A: elems 0..15 (lower indices)
                    bool gt = pm > bd0;
                    bd0 = gt ? pm : bd0;
                    bi0 = gt ? pi : bi0;
                } else {                 // chain B: elems 16..31
                    bool gt = pm > bd1;
                    bd1 = gt ? pm : bd1;
                    bi1 = gt ? pi : bi1;
                }
            }
            unsigned long long key0 =
                ((unsigned long long)__float_as_uint(bd0) << 32) |
                (unsigned long long)(~(unsigned int)(t + (bi0 << 8)));
            unsigned long long key1 =
                ((unsigned long long)__float_as_uint(bd1) << 32) |
                (unsigned long long)(~(unsigned int)(t + (bi1 << 8)));
            unsigned long long key = u64max(key0, key1);
            key = dpp_wave_max(key);
            if (lane == 63) wred[(j & 1) * 4 + wv] = key;
            fps_bar();
            int cur;
            {
                const unsigned long long* wr = &wred[(j & 1) * 4];
                ulonglong2 p01 = *(const ulonglong2*)&wr[0];
                ulonglong2 p23 = *(const ulonglong2*)&wr[2];
                unsigned long long m = u64max(u64max(p01.x, p01.y),
                                              u64max(p23.x, p23.y));
                cur = (int)(~(unsigned int)(m & 0xffffffffull));
            }
            {   // one contiguous 12B broadcast read (wave-uniform address)
                const float* cp = &sxyz[cur * 3];
                float3 c = *(const float3*)cp;
                lx = c.x; ly = c.y; lz = c.z;
            }
            if (t == 0) {
                outb[j * 3 + 0] = lx;
                outb[j * 3 + 1] = ly;
                outb[j * 3 + 2] = lz;
                __hip_atomic_store(&selb[j], (unsigned)(cur + 1),
                                   __ATOMIC_RELAXED, __HIP_MEMORY_SCOPE_AGENT);
            }
        }
    } else {
        // =================== consumer: ballq + MFMA MLP =====================
        const int i = blockIdx.x - BB;
        const int b = i & 7;                   // batch
        const int g = i >> 3;                  // centroid group (4 centroids)
        unsigned short* s_x = (unsigned short*)smem;            // 128*XS
        unsigned short* s_h = (unsigned short*)(smem + 26624);  // 128*HS
        unsigned short* s_w12 = (unsigned short*)(smem + 45056);// 11264 elems
        int* s_gi = (int*)(smem + 67584);                       // 128
        int* s_sel4 = (int*)(smem + 68096);                     // 4

        const int w = t >> 6;
        const int col = lane & 15;
        const int quad = lane >> 4;

        // ---- stage w1, w2 (independent of fps progress) ----
        {
            int o = t >> 2, part = t & 3;
            const float* w1r = w1 + o * 67;
#pragma unroll
            for (int ii = 0; ii < 26; ++ii) {
                int c = part * 26 + ii;
                float v = 0.0f;
                if (c < 64) v = w1r[3 + c];           // permuted: feats first
                else if (c < 67) v = w1r[c - 64];     // then xyz cols
                s_w12[o * XS + c] = f2bf(v);
            }
            const float* w2r = w2 + o * 64 + part * 16;
#pragma unroll
            for (int ii = 0; ii < 8; ++ii) {
                unsigned pk = (unsigned)f2bf(w2r[2 * ii]) |
                              ((unsigned)f2bf(w2r[2 * ii + 1]) << 16);
                *(unsigned*)&s_w12[6656 + o * HS + part * 16 + 2 * ii] = pk;
            }
        }

        // ---- spin for the 4 centroid indices ----
        if (t < 4) {
            unsigned* sp = sel + b * NPOINT + (g << 2) + t;
            unsigned v;
            while ((( v = __hip_atomic_load(sp, __ATOMIC_RELAXED,
                                            __HIP_MEMORY_SCOPE_AGENT)) - 1u) > 8191u)
                __builtin_amdgcn_s_sleep(32);
            s_sel4[t] = (int)(v - 1u);
        }
        __syncthreads();

        // ---- ball query: wave w -> centroid s_sel4[w] ----
        {
            const int cidx = s_sel4[w];
            const float* base = xyz + (size_t)b * NN * 3;
            const float cx = base[cidx * 3 + 0];   // bit-identical to new_xyz
            const float cy = base[cidx * 3 + 1];
            const float cz = base[cidx * 3 + 2];
            const float R2 = (float)(0.4 * 0.4);   // 0.15999999642f

            int have = 0;
            for (int chunk = 0; chunk < (NN / 64) && have < NSAMPLE; ++chunk) {
                int p = (chunk << 6) + lane;
                float dx = __fsub_rn(cx, base[p * 3 + 0]);
                float dy = __fsub_rn(cy, base[p * 3 + 1]);
                float dz = __fsub_rn(cz, base[p * 3 + 2]);
                float d2 = __fadd_rn(__fadd_rn(__fmul_rn(dx, dx), __fmul_rn(dy, dy)),
                                     __fmul_rn(dz, dz));
                bool in = d2 < R2;
                unsigned long long m = __ballot(in);
                int pre = __popcll(m & ((1ull << lane) - 1ull));
                int slot = have + pre;
                if (in && slot < NSAMPLE) s_gi[w * NSAMPLE + slot] = p;
                have += (int)__popcll(m);
            }
            if (lane < NSAMPLE) {
                int first = s_gi[w * NSAMPLE];    // centroid always hits
                int v = (lane < have) ? s_gi[w * NSAMPLE + lane] : first;
                s_gi[w * NSAMPLE + lane] = v;
            }
        }
        __syncthreads();

        // ---- gather x = [feat(64) | xyz_rel(3) | zeros] in bf16 ----
        {
            int k = t >> 1, half = t & 1;
            int row = s_gi[k];
            const float4* frow =
                (const float4*)(features + ((size_t)b * NN + row) * 64) + half * 8;
            unsigned short* xr = &s_x[k * XS + half * 32];
#pragma unroll
            for (int ii = 0; ii < 8; ++ii) {
                float4 v = frow[ii];
                unsigned lo = (unsigned)f2bf(v.x) | ((unsigned)f2bf(v.y) << 16);
                unsigned hi = (unsigned)f2bf(v.z) | ((unsigned)f2bf(v.w) << 16);
                *(uint2*)(xr + ii * 4) = make_uint2(lo, hi);
            }
        }
        if (t < 128) {
            int k = t;
            int row = s_gi[k];
            int cidx = s_sel4[k >> 5];
            const float* pr = xyz + ((size_t)b * NN + row) * 3;
            const float* cr = xyz + ((size_t)b * NN + cidx) * 3;
            s_x[k * XS + 64] = f2bf(pr[0] - cr[0]);
            s_x[k * XS + 65] = f2bf(pr[1] - cr[1]);
            s_x[k * XS + 66] = f2bf(pr[2] - cr[2]);
            s_x[k * XS + 67] = 0;
            unsigned* z = (unsigned*)&s_x[k * XS + 68];
#pragma unroll
            for (int ii = 0; ii < 14; ++ii) z[ii] = 0;    // cols 68..95
        }
        __syncthreads();

        const int mbase = w * 32;

        // ---- Layer 1: [128 x 96] x [96 -> 64] ----
        floatx4 acc[2][4] = {};
        for (int kk = 0; kk < 3; ++kk) {
            short8 a0 = *(const short8*)&s_x[(mbase + col) * XS + kk * 32 + quad * 8];
            short8 a1 = *(const short8*)&s_x[(mbase + 16 + col) * XS + kk * 32 + quad * 8];
#pragma unroll
            for (int nt = 0; nt < 4; ++nt) {
                short8 bfr = *(const short8*)&s_w12[(nt * 16 + col) * XS + kk * 32 + quad * 8];
                acc[0][nt] = __builtin_amdgcn_mfma_f32_16x16x32_bf16(a0, bfr, acc[0][nt], 0, 0, 0);
                acc[1][nt] = __builtin_amdgcn_mfma_f32_16x16x32_bf16(a1, bfr, acc[1][nt], 0, 0, 0);
            }
        }
#pragma unroll
        for (int nt = 0; nt < 4; ++nt) {
            float bb = b1[nt * 16 + col];
#pragma unroll
            for (int mt = 0; mt < 2; ++mt)
#pragma unroll
                for (int r = 0; r < 4; ++r) {
                    float v = fmaxf(acc[mt][nt][r] + bb, 0.0f);
                    s_h[(mbase + mt * 16 + quad * 4 + r) * HS + nt * 16 + col] = f2bf(v);
                }
        }
        __syncthreads();

        // ---- Layer 2: [128 x 64] x [64 -> 64], h2 -> s_x region ----
        floatx4 acc2[2][4] = {};
        for (int kk = 0; kk < 2; ++kk) {
            short8 a0 = *(const short8*)&s_h[(mbase + col) * HS + kk * 32 + quad * 8];
            short8 a1 = *(const short8*)&s_h[(mbase + 16 + col) * HS + kk * 32 + quad * 8];
#pragma unroll
            for (int nt = 0; nt < 4; ++nt) {
                short8 bfr = *(const short8*)&s_w12[6656 + (nt * 16 + col) * HS + kk * 32 + quad * 8];
                acc2[0][nt] = __builtin_amdgcn_mfma_f32_16x16x32_bf16(a0, bfr, acc2[0][nt], 0, 0, 0);
                acc2[1][nt] = __builtin_amdgcn_mfma_f32_16x16x32_bf16(a1, bfr, acc2[1][nt], 0, 0, 0);
            }
        }
        unsigned short* s_h2 = s_x;  // x dead after L1
#pragma unroll
        for (int nt = 0; nt < 4; ++nt) {
            float bb = b2[nt * 16 + col];
#pragma unroll
            for (int mt = 0; mt < 2; ++mt)
#pragma unroll
                for (int r = 0; r < 4; ++r) {
                    float v = fmaxf(acc2[mt][nt][r] + bb, 0.0f);
                    s_h2[(mbase + mt * 16 + quad * 4 + r) * HS + nt * 16 + col] = f2bf(v);
                }
        }
        __syncthreads();   // h2 complete; all w2 reads done

        // ---- stage w3 [128][HS] over w1/w2 ----
        {
            int o = t >> 1, half = t & 1;
            const float* w3r = w3 + o * 64 + half * 32;
#pragma unroll
            for (int ii = 0; ii < 16; ++ii) {
                unsigned pk = (unsigned)f2bf(w3r[2 * ii]) |
                              ((unsigned)f2bf(w3r[2 * ii + 1]) << 16);
                *(unsigned*)&s_w12[o * HS + half * 32 + 2 * ii] = pk;
            }
        }
        __syncthreads();

        // ---- Layer 3: [128 x 64] x [64 -> 128], fused maxpool+bias+relu ----
        floatx4 c3[2][8] = {};
        for (int kk = 0; kk < 2; ++kk) {
            short8 a0 = *(const short8*)&s_h2[(mbase + col) * HS + kk * 32 + quad * 8];
            short8 a1 = *(const short8*)&s_h2[(mbase + 16 + col) * HS + kk * 32 + quad * 8];
#pragma unroll
            for (int nt = 0; nt < 8; ++nt) {
                short8 bfr = *(const short8*)&s_w12[(nt * 16 + col) * HS + kk * 32 + quad * 8];
                c3[0][nt] = __builtin_amdgcn_mfma_f32_16x16x32_bf16(a0, bfr, c3[0][nt], 0, 0, 0);
                c3[1][nt] = __builtin_amdgcn_mfma_f32_16x16x32_bf16(a1, bfr, c3[1][nt], 0, 0, 0);
            }
        }
        {
            int gg = (g << 2) + w;
            float* ob = out_feat + (size_t)b * (128 * 1024) + gg;
#pragma unroll
            for (int nt = 0; nt < 8; ++nt) {
                float m = fmaxf(fmaxf(fmaxf(c3[0][nt][0], c3[0][nt][1]),
                                      fmaxf(c3[0][nt][2], c3[0][nt][3])),
                                fmaxf(fmaxf(c3[1][nt][0], c3[1][nt][1]),
                                      fmaxf(c3[1][nt][2], c3[1][nt][3])));
                m = fmaxf(m, __shfl_xor(m, 16));
                m = fmaxf(m, __shfl_xor(m, 32));
                if (lane < 16) {
                    float v = fmaxf(m + b3[nt * 16 + lane], 0.0f);
                    ob[(size_t)(nt * 16 + lane) * 1024] = v;
                }
            }
        }
    }
}

extern "C" void kernel_launch(void* const* d_in, const int* in_sizes, int n_in,
                              void* d_out, int out_size, void* d_ws, size_t ws_size,
                              hipStream_t stream) {
    const float* xyz      = (const float*)d_in[0];
    const float* features = (const float*)d_in[1];
    const float* w1       = (const float*)d_in[2];
    const float* b1       = (const float*)d_in[3];
    const float* w2       = (const float*)d_in[4];
    const float* b2       = (const float*)d_in[5];
    const float* w3       = (const float*)d_in[6];
    const float* b3       = (const float*)d_in[7];

    float* out      = (float*)d_out;
    float* new_xyz  = out;                         // B*NPOINT*3
    float* out_feat = out + BB * NPOINT * 3;       // B*128*NPOINT
    unsigned* sel   = (unsigned*)d_ws;             // B*NPOINT u32; poison = not-ready

    mega_kernel<<<BB + (BB * NPOINT) / 4, 256, 0, stream>>>(
        xyz, features, w1, b1, w2, b2, w3, b3, new_xyz, out_feat, sel);
}